// Round 1
// baseline (726.325 us; speedup 1.0000x reference)
//
#include <hip/hip_runtime.h>
#include <hip/hip_bf16.h>
#include <cstdint>

// Problem: B=32, T1=T2=512, D=128, gamma=1.0
// out[b] = softDTW( 1 - cos_sim(x[b], y[b]) )
//
// ws layout (floats):
//   xn   : 32*512*128           =  2,097,152
//   yn   : 32*512*128           =  2,097,152
//   skew : 32*1023*512          = 16,760,832   (cost/ln2 in anti-diagonal layout)
// total ~80 MB.

#define BT      32
#define TLEN    512
#define DF      128
#define NDIAG   1023          // kd = 0..1022  (kd = i-1 + j-1)
#define BIGV    1e30f
#define INV_LN2 1.44269504088896340f
#define LN2     0.69314718055994531f

// ---------------------------------------------------------------- normalize
__global__ __launch_bounds__(256) void sdtw_norm(const float* __restrict__ in,
                                                 float* __restrict__ out) {
    int row = blockIdx.x * 4 + (threadIdx.x >> 6);   // 4 waves per block, 1 row each
    int t   = threadIdx.x & 63;
    const float2* ip = reinterpret_cast<const float2*>(in + (size_t)row * DF);
    float2 v = ip[t];
    float s = v.x * v.x + v.y * v.y;
    #pragma unroll
    for (int o = 32; o; o >>= 1) s += __shfl_xor(s, o);
    float scale = 1.0f / fmaxf(sqrtf(s), 1e-12f);
    float2 w; w.x = v.x * scale; w.y = v.y * scale;
    reinterpret_cast<float2*>(out + (size_t)row * DF)[t] = w;
}

// ------------------------------------------------- cosine-dist GEMM -> skew
// 128x128 tile per block, 256 threads, 8x8 per thread, K staged in chunks of 32.
#define KC   32
#define SPAD 132   // k-major LDS stride (floats): 528B, 16B-aligned reads

__global__ __launch_bounds__(256) void sdtw_gemm_skew(const float* __restrict__ xn,
                                                      const float* __restrict__ yn,
                                                      float* __restrict__ skew) {
    __shared__ float smem[16640];            // max(2*KC*SPAD=8448, 128*130=16640)
    float* xs = smem;                        // [KC][SPAD] transposed: xs[k][row]
    float* ys = smem + KC * SPAD;            // [KC][SPAD]

    const int b  = blockIdx.z;
    const int r0 = blockIdx.y * 128;
    const int c0 = blockIdx.x * 128;
    const int tid = threadIdx.x;
    const int tx = tid & 15, ty = tid >> 4;

    const float* xb = xn + ((size_t)b * TLEN + r0) * DF;
    const float* yb = yn + ((size_t)b * TLEN + c0) * DF;

    float acc[8][8];
    #pragma unroll
    for (int i = 0; i < 8; ++i)
        #pragma unroll
        for (int j = 0; j < 8; ++j) acc[i][j] = 0.0f;

    for (int kb = 0; kb < DF; kb += KC) {
        __syncthreads();
        // stage 128 rows x KC k's of x and y, transposed into LDS
        #pragma unroll
        for (int i = 0; i < 4; ++i) {
            int g   = tid + i * 256;          // 0..1023
            int row = g >> 3;                 // 8 float4 per row-chunk
            int kq  = g & 7;
            float4 vx = *reinterpret_cast<const float4*>(xb + (size_t)row * DF + kb + kq * 4);
            float4 vy = *reinterpret_cast<const float4*>(yb + (size_t)row * DF + kb + kq * 4);
            xs[(kq * 4 + 0) * SPAD + row] = vx.x;
            xs[(kq * 4 + 1) * SPAD + row] = vx.y;
            xs[(kq * 4 + 2) * SPAD + row] = vx.z;
            xs[(kq * 4 + 3) * SPAD + row] = vx.w;
            ys[(kq * 4 + 0) * SPAD + row] = vy.x;
            ys[(kq * 4 + 1) * SPAD + row] = vy.y;
            ys[(kq * 4 + 2) * SPAD + row] = vy.z;
            ys[(kq * 4 + 3) * SPAD + row] = vy.w;
        }
        __syncthreads();
        #pragma unroll
        for (int k = 0; k < KC; ++k) {
            float ax[8], ay[8];
            *reinterpret_cast<float4*>(&ax[0]) = *reinterpret_cast<const float4*>(&xs[k * SPAD + ty * 8]);
            *reinterpret_cast<float4*>(&ax[4]) = *reinterpret_cast<const float4*>(&xs[k * SPAD + ty * 8 + 4]);
            *reinterpret_cast<float4*>(&ay[0]) = *reinterpret_cast<const float4*>(&ys[k * SPAD + tx * 8]);
            *reinterpret_cast<float4*>(&ay[4]) = *reinterpret_cast<const float4*>(&ys[k * SPAD + tx * 8 + 4]);
            #pragma unroll
            for (int i = 0; i < 8; ++i)
                #pragma unroll
                for (int j = 0; j < 8; ++j)
                    acc[i][j] = fmaf(ax[i], ay[j], acc[i][j]);
        }
    }

    // epilogue: cost/ln2 into LDS tile [128][130] (stride 130 -> anti-diag reads conflict-free)
    __syncthreads();
    float* cs = smem;
    #pragma unroll
    for (int i = 0; i < 8; ++i)
        #pragma unroll
        for (int j = 0; j < 8; ++j)
            cs[(ty * 8 + i) * 130 + tx * 8 + j] = (1.0f - acc[i][j]) * INV_LN2;
    __syncthreads();

    // cooperative anti-diagonal writes: skew[kd*512 + r] contiguous in r
    float* sk = skew + (size_t)b * (NDIAG * TLEN);
    const int wv = tid >> 6, l = tid & 63;
    for (int dd = wv; dd < 255; dd += 4) {
        int lo = max(0, dd - 127), hi = min(127, dd);
        size_t base = (size_t)(r0 + c0 + dd) * TLEN + r0;
        for (int rb = lo; rb <= hi; rb += 64) {
            int rl = rb + l;
            if (rl <= hi) sk[base + rl] = cs[rl * 129 + dd];   // rl*130 + (dd-rl)
        }
    }
}

// ----------------------------------------------------------------- DTW DP
// One wave per batch. Lane t owns rows r = s*64+t, s=0..7.
// dm1[s] = A_{k-1}[r], dm2[s] = A_{k-2}[r] where A_d[r] = R(r+1, d-r-1).
// Triple-buffered cost prefetch (depth 2). All array indices compile-time.

__device__ __forceinline__ void dp_issue(const float* __restrict__ sk, int kd, int t,
                                         float (&buf)[8]) {
    int rlo = kd - 511, rhi = kd;                  // valid rows of diag kd
    int slo = max(0, rlo) >> 6, shi = min(511, rhi) >> 6;
    const float* p = sk + (size_t)kd * TLEN + t;
    #pragma unroll
    for (int s = 0; s < 8; ++s) {
        if (s >= slo && s <= shi) buf[s] = p[s * 64];
    }
}

__device__ __forceinline__ void dp_step(int k, int t, const float (&cb)[8],
                                        float (&dm1)[8], float (&dm2)[8]) {
    int rlo = k - 513, rhi = k - 2;
    int slo = max(0, rlo) >> 6, shi = min(511, rhi) >> 6;
    #pragma unroll
    for (int s = 7; s >= 0; --s) {                 // descending: in-place update safe
        if (s < slo || s > shi) continue;          // wave-uniform guard
        int  r     = s * 64 + t;
        bool valid = (r >= rlo) && (r <= rhi);
        float left = dm1[s];                       // R(i, j-1)
        float pu = __shfl_up(dm1[s], 1);
        float pd = __shfl_up(dm2[s], 1);
        float bu, bd;
        if (s > 0) {                               // compile-time branch
            bu = __shfl(dm1[s - 1], 63);
            bd = __shfl(dm2[s - 1], 63);
        } else {
            bu = BIGV;
            bd = (k == 2) ? 0.0f : BIGV;           // R(0,0)=0 enters at k=2 only
        }
        float up = (t == 0) ? bu : pu;             // R(i-1, j)
        float dg = (t == 0) ? bd : pd;             // R(i-1, j-1)
        float m  = fminf(fminf(dg, left), up);
        float e  = __builtin_amdgcn_exp2f(m - dg)
                 + __builtin_amdgcn_exp2f(m - left)
                 + __builtin_amdgcn_exp2f(m - up);
        float val = cb[s] + m - __builtin_amdgcn_logf(e);   // log2-space softmin
        dm2[s] = dm1[s];
        dm1[s] = valid ? val : BIGV;
    }
}

__global__ __launch_bounds__(64) void sdtw_dp(const float* __restrict__ skew,
                                              float* __restrict__ out) {
    const int b = blockIdx.x;
    const int t = threadIdx.x;
    const float* sk = skew + (size_t)b * (NDIAG * TLEN);

    float dm1[8], dm2[8], bA[8], bB[8], bC[8];
    #pragma unroll
    for (int s = 0; s < 8; ++s) { dm1[s] = BIGV; dm2[s] = BIGV; }

    dp_issue(sk, 0, t, bA);            // diag k=2
    dp_issue(sk, 1, t, bB);            // diag k=3

    for (int k = 2; k <= 1024; k += 3) {           // 1023 = 3*341 exact
        dp_issue(sk, min(k, 1022), t, bC);         // for diag k+2
        dp_step(k, t, bA, dm1, dm2);
        dp_issue(sk, min(k + 1, 1022), t, bA);     // for diag k+3
        dp_step(k + 1, t, bB, dm1, dm2);
        dp_issue(sk, min(k + 2, 1022), t, bB);     // for diag k+4
        dp_step(k + 2, t, bC, dm1, dm2);
    }
    if (t == 63) out[b] = dm1[7] * LN2;            // R'(512,512) * ln2
}

// ---------------------------------------------------------------- launcher
extern "C" void kernel_launch(void* const* d_in, const int* in_sizes, int n_in,
                              void* d_out, int out_size, void* d_ws, size_t ws_size,
                              hipStream_t stream) {
    const float* x = (const float*)d_in[0];
    const float* y = (const float*)d_in[1];
    float* outp = (float*)d_out;

    float* xn   = (float*)d_ws;                       // 2,097,152 floats
    float* yn   = xn + (size_t)BT * TLEN * DF;        // 2,097,152 floats
    float* skew = yn + (size_t)BT * TLEN * DF;        // 16,760,832 floats

    // normalize rows of x and y  (16384 rows each, 4 rows/block)
    sdtw_norm<<<dim3(BT * TLEN / 4), dim3(256), 0, stream>>>(x, xn);
    sdtw_norm<<<dim3(BT * TLEN / 4), dim3(256), 0, stream>>>(y, yn);

    // cosine distance -> skewed cost matrix
    sdtw_gemm_skew<<<dim3(4, 4, BT), dim3(256), 0, stream>>>(xn, yn, skew);

    // soft-DTW DP, one wave per batch
    sdtw_dp<<<dim3(BT), dim3(64), 0, stream>>>(skew, outp);
}

// Round 2
// 374.963 us; speedup vs baseline: 1.9371x; 1.9371x over previous
//
#include <hip/hip_runtime.h>
#include <hip/hip_bf16.h>
#include <cstdint>

// Problem: B=32, T1=T2=512, D=128, gamma=1.0
// out[b] = softDTW( 1 - cos_sim(x[b], y[b]) )
//
// ws layout (floats):
//   xn   : 32*512*128           =  2,097,152
//   yn   : 32*512*128           =  2,097,152
//   skew : 32*1023*512          = 16,760,832   (cost/ln2 in anti-diagonal layout)

#define BT      32
#define TLEN    512
#define DF      128
#define NDIAG   1023          // kd = 0..1022  (kd = i-1 + j-1)
#define BIGV    1e30f
#define INV_LN2 1.44269504088896340f
#define LN2     0.69314718055994531f

// ---------------------------------------------------------------- normalize
__global__ __launch_bounds__(256) void sdtw_norm(const float* __restrict__ in,
                                                 float* __restrict__ out) {
    int row = blockIdx.x * 4 + (threadIdx.x >> 6);   // 4 waves per block, 1 row each
    int t   = threadIdx.x & 63;
    const float2* ip = reinterpret_cast<const float2*>(in + (size_t)row * DF);
    float2 v = ip[t];
    float s = v.x * v.x + v.y * v.y;
    #pragma unroll
    for (int o = 32; o; o >>= 1) s += __shfl_xor(s, o);
    float scale = 1.0f / fmaxf(sqrtf(s), 1e-12f);
    float2 w; w.x = v.x * scale; w.y = v.y * scale;
    reinterpret_cast<float2*>(out + (size_t)row * DF)[t] = w;
}

// ------------------------------------------------- cosine-dist GEMM -> skew
#define KC   32
#define SPAD 132

__global__ __launch_bounds__(256) void sdtw_gemm_skew(const float* __restrict__ xn,
                                                      const float* __restrict__ yn,
                                                      float* __restrict__ skew) {
    __shared__ float smem[16640];
    float* xs = smem;                        // [KC][SPAD] transposed: xs[k][row]
    float* ys = smem + KC * SPAD;

    const int b  = blockIdx.z;
    const int r0 = blockIdx.y * 128;
    const int c0 = blockIdx.x * 128;
    const int tid = threadIdx.x;
    const int tx = tid & 15, ty = tid >> 4;

    const float* xb = xn + ((size_t)b * TLEN + r0) * DF;
    const float* yb = yn + ((size_t)b * TLEN + c0) * DF;

    float acc[8][8];
    #pragma unroll
    for (int i = 0; i < 8; ++i)
        #pragma unroll
        for (int j = 0; j < 8; ++j) acc[i][j] = 0.0f;

    for (int kb = 0; kb < DF; kb += KC) {
        __syncthreads();
        #pragma unroll
        for (int i = 0; i < 4; ++i) {
            int g   = tid + i * 256;
            int row = g >> 3;
            int kq  = g & 7;
            float4 vx = *reinterpret_cast<const float4*>(xb + (size_t)row * DF + kb + kq * 4);
            float4 vy = *reinterpret_cast<const float4*>(yb + (size_t)row * DF + kb + kq * 4);
            xs[(kq * 4 + 0) * SPAD + row] = vx.x;
            xs[(kq * 4 + 1) * SPAD + row] = vx.y;
            xs[(kq * 4 + 2) * SPAD + row] = vx.z;
            xs[(kq * 4 + 3) * SPAD + row] = vx.w;
            ys[(kq * 4 + 0) * SPAD + row] = vy.x;
            ys[(kq * 4 + 1) * SPAD + row] = vy.y;
            ys[(kq * 4 + 2) * SPAD + row] = vy.z;
            ys[(kq * 4 + 3) * SPAD + row] = vy.w;
        }
        __syncthreads();
        #pragma unroll
        for (int k = 0; k < KC; ++k) {
            float ax[8], ay[8];
            *reinterpret_cast<float4*>(&ax[0]) = *reinterpret_cast<const float4*>(&xs[k * SPAD + ty * 8]);
            *reinterpret_cast<float4*>(&ax[4]) = *reinterpret_cast<const float4*>(&xs[k * SPAD + ty * 8 + 4]);
            *reinterpret_cast<float4*>(&ay[0]) = *reinterpret_cast<const float4*>(&ys[k * SPAD + tx * 8]);
            *reinterpret_cast<float4*>(&ay[4]) = *reinterpret_cast<const float4*>(&ys[k * SPAD + tx * 8 + 4]);
            #pragma unroll
            for (int i = 0; i < 8; ++i)
                #pragma unroll
                for (int j = 0; j < 8; ++j)
                    acc[i][j] = fmaf(ax[i], ay[j], acc[i][j]);
        }
    }

    __syncthreads();
    float* cs = smem;
    #pragma unroll
    for (int i = 0; i < 8; ++i)
        #pragma unroll
        for (int j = 0; j < 8; ++j)
            cs[(ty * 8 + i) * 130 + tx * 8 + j] = (1.0f - acc[i][j]) * INV_LN2;
    __syncthreads();

    float* sk = skew + (size_t)b * (NDIAG * TLEN);
    const int wv = tid >> 6, l = tid & 63;
    for (int dd = wv; dd < 255; dd += 4) {
        int lo = max(0, dd - 127), hi = min(127, dd);
        size_t base = (size_t)(r0 + c0 + dd) * TLEN + r0;
        for (int rb = lo; rb <= hi; rb += 64) {
            int rl = rb + l;
            if (rl <= hi) sk[base + rl] = cs[rl * 129 + dd];   // rl*130 + (dd-rl)
        }
    }
}

// ----------------------------------------------------------------- DTW DP
// One wave per batch. Lane t owns CONTIGUOUS rows r = t*8+q, q=0..7.
// A_d[r] = R(r+1, d-r-1). PN = diag k-1 (read), PO = diag k-2 (read, overwritten
// in place with diag k; descending q makes in-place safe).
// Cross-lane traffic: ONE __shfl_up per step (slot-7 value of diag k-1);
// the diag k-2 shuffle is the previous step's, carried in sh_prev.

#define DP_STEP(CA, CB, PN, PO, DBND)                                          \
  {                                                                            \
    float sh_cur = __shfl_up(PN[7], 1);                                        \
    _Pragma("unroll")                                                          \
    for (int q = 7; q >= 0; --q) {                                             \
      float left = PN[q];                           /* R(i, j-1)   */          \
      float up   = (q == 0) ? ((t == 0) ? vBig : sh_cur) : PN[q - 1];          \
      float dg   = (q == 0) ? ((t == 0) ? (DBND) : sh_prev) : PO[q - 1];       \
      float cq   = (q < 4) ? ((q == 0) ? CA.x : (q == 1) ? CA.y                \
                              : (q == 2) ? CA.z : CA.w)                        \
                           : ((q == 4) ? CB.x : (q == 5) ? CB.y                \
                              : (q == 6) ? CB.z : CB.w);                       \
      int   jm1  = vb - q;                          /* j-1 = k-2-r */          \
      float m    = fminf(fminf(dg, left), up);                                 \
      float e    = __builtin_amdgcn_exp2f(m - dg)                              \
                 + __builtin_amdgcn_exp2f(m - left)                            \
                 + __builtin_amdgcn_exp2f(m - up);                             \
      float val  = cq + m - __builtin_amdgcn_logf(e);                          \
      PO[q] = ((unsigned)jm1 < 512u) ? val : vBig;                             \
    }                                                                          \
    sh_prev = sh_cur;                                                          \
    vb += 1;                                                                   \
  }

__global__ __launch_bounds__(64) void sdtw_dp(const float* __restrict__ skew,
                                              float* __restrict__ out) {
    const int b = blockIdx.x;
    const int t = threadIdx.x;
    const float* sk = skew + (size_t)b * (NDIAG * TLEN);

    float P[8], Q[8];
    #pragma unroll
    for (int q = 0; q < 8; ++q) { P[q] = BIGV; Q[q] = BIGV; }
    float vBig    = BIGV;
    float sh_prev = BIGV;
    int   vb      = -t * 8;                 // (k-2) - t*8 at k=2

    // cost prefetch: 4 buffers (float4 pairs), depth 4 steps
    const float* pl = sk + t * 8;
    int kd_load = 0;
    float4 c0a, c0b, c1a, c1b, c2a, c2b, c3a, c3b;
    c0a = *(const float4*)pl; c0b = *(const float4*)(pl + 4); pl += TLEN;
    c1a = *(const float4*)pl; c1b = *(const float4*)(pl + 4); pl += TLEN;
    c2a = *(const float4*)pl; c2b = *(const float4*)(pl + 4); pl += TLEN;
    c3a = *(const float4*)pl; c3b = *(const float4*)(pl + 4); pl += TLEN;
    kd_load = 4;

    // 256 groups x 4 steps = k = 2..1025 (step 1025 is a discarded dummy;
    // it writes P only, the answer lands in Q at k=1024).
    for (int g = 0; g < 256; ++g) {
        float db0 = (g == 0) ? 0.0f : BIGV;   // R(0,0)=0 enters only at k=2

        DP_STEP(c0a, c0b, P, Q, db0);
        if (kd_load < NDIAG) { c0a = *(const float4*)pl; c0b = *(const float4*)(pl + 4); }
        pl += TLEN; ++kd_load;

        DP_STEP(c1a, c1b, Q, P, vBig);
        if (kd_load < NDIAG) { c1a = *(const float4*)pl; c1b = *(const float4*)(pl + 4); }
        pl += TLEN; ++kd_load;

        DP_STEP(c2a, c2b, P, Q, vBig);
        if (kd_load < NDIAG) { c2a = *(const float4*)pl; c2b = *(const float4*)(pl + 4); }
        pl += TLEN; ++kd_load;

        DP_STEP(c3a, c3b, Q, P, vBig);
        if (kd_load < NDIAG) { c3a = *(const float4*)pl; c3b = *(const float4*)(pl + 4); }
        pl += TLEN; ++kd_load;
    }

    if (t == 63) out[b] = Q[7] * LN2;       // R'(512,512) * ln2
}

// ---------------------------------------------------------------- launcher
extern "C" void kernel_launch(void* const* d_in, const int* in_sizes, int n_in,
                              void* d_out, int out_size, void* d_ws, size_t ws_size,
                              hipStream_t stream) {
    const float* x = (const float*)d_in[0];
    const float* y = (const float*)d_in[1];
    float* outp = (float*)d_out;

    float* xn   = (float*)d_ws;
    float* yn   = xn + (size_t)BT * TLEN * DF;
    float* skew = yn + (size_t)BT * TLEN * DF;

    sdtw_norm<<<dim3(BT * TLEN / 4), dim3(256), 0, stream>>>(x, xn);
    sdtw_norm<<<dim3(BT * TLEN / 4), dim3(256), 0, stream>>>(y, yn);
    sdtw_gemm_skew<<<dim3(4, 4, BT), dim3(256), 0, stream>>>(xn, yn, skew);
    sdtw_dp<<<dim3(BT), dim3(64), 0, stream>>>(skew, outp);
}

// Round 3
// 256.741 us; speedup vs baseline: 2.8290x; 1.4605x over previous
//
#include <hip/hip_runtime.h>
#include <hip/hip_bf16.h>
#include <cstdint>

// Problem: B=32, T1=T2=512, D=128, gamma=1.0
// out[b] = softDTW( 1 - cos_sim(x[b], y[b]) )
//
// ws layout (floats):
//   xn   : 32*512*128           =  2,097,152
//   yn   : 32*512*128           =  2,097,152
//   skew : 32*1023*512          = 16,760,832   (cost/ln2 in anti-diagonal layout)

#define BT      32
#define TLEN    512
#define DF      128
#define NDIAG   1023          // kd = 0..1022  (kd = i-1 + j-1)
#define BIGV    1e30f
#define INV_LN2 1.44269504088896340f
#define LN2     0.69314718055994531f

// ---------------------------------------------------------------- normalize
__global__ __launch_bounds__(256) void sdtw_norm(const float* __restrict__ in,
                                                 float* __restrict__ out) {
    int row = blockIdx.x * 4 + (threadIdx.x >> 6);
    int t   = threadIdx.x & 63;
    const float2* ip = reinterpret_cast<const float2*>(in + (size_t)row * DF);
    float2 v = ip[t];
    float s = v.x * v.x + v.y * v.y;
    #pragma unroll
    for (int o = 32; o; o >>= 1) s += __shfl_xor(s, o);
    float scale = 1.0f / fmaxf(sqrtf(s), 1e-12f);
    float2 w; w.x = v.x * scale; w.y = v.y * scale;
    reinterpret_cast<float2*>(out + (size_t)row * DF)[t] = w;
}

// ------------------------------------------------- cosine-dist GEMM -> skew
#define KC   32
#define SPAD 132

__global__ __launch_bounds__(256) void sdtw_gemm_skew(const float* __restrict__ xn,
                                                      const float* __restrict__ yn,
                                                      float* __restrict__ skew) {
    __shared__ float smem[16640];
    float* xs = smem;                        // [KC][SPAD] transposed: xs[k][row]
    float* ys = smem + KC * SPAD;

    const int b  = blockIdx.z;
    const int r0 = blockIdx.y * 128;
    const int c0 = blockIdx.x * 128;
    const int tid = threadIdx.x;
    const int tx = tid & 15, ty = tid >> 4;

    const float* xb = xn + ((size_t)b * TLEN + r0) * DF;
    const float* yb = yn + ((size_t)b * TLEN + c0) * DF;

    float acc[8][8];
    #pragma unroll
    for (int i = 0; i < 8; ++i)
        #pragma unroll
        for (int j = 0; j < 8; ++j) acc[i][j] = 0.0f;

    for (int kb = 0; kb < DF; kb += KC) {
        __syncthreads();
        #pragma unroll
        for (int i = 0; i < 4; ++i) {
            int g   = tid + i * 256;
            int row = g >> 3;
            int kq  = g & 7;
            float4 vx = *reinterpret_cast<const float4*>(xb + (size_t)row * DF + kb + kq * 4);
            float4 vy = *reinterpret_cast<const float4*>(yb + (size_t)row * DF + kb + kq * 4);
            xs[(kq * 4 + 0) * SPAD + row] = vx.x;
            xs[(kq * 4 + 1) * SPAD + row] = vx.y;
            xs[(kq * 4 + 2) * SPAD + row] = vx.z;
            xs[(kq * 4 + 3) * SPAD + row] = vx.w;
            ys[(kq * 4 + 0) * SPAD + row] = vy.x;
            ys[(kq * 4 + 1) * SPAD + row] = vy.y;
            ys[(kq * 4 + 2) * SPAD + row] = vy.z;
            ys[(kq * 4 + 3) * SPAD + row] = vy.w;
        }
        __syncthreads();
        #pragma unroll
        for (int k = 0; k < KC; ++k) {
            float ax[8], ay[8];
            *reinterpret_cast<float4*>(&ax[0]) = *reinterpret_cast<const float4*>(&xs[k * SPAD + ty * 8]);
            *reinterpret_cast<float4*>(&ax[4]) = *reinterpret_cast<const float4*>(&xs[k * SPAD + ty * 8 + 4]);
            *reinterpret_cast<float4*>(&ay[0]) = *reinterpret_cast<const float4*>(&ys[k * SPAD + tx * 8]);
            *reinterpret_cast<float4*>(&ay[4]) = *reinterpret_cast<const float4*>(&ys[k * SPAD + tx * 8 + 4]);
            #pragma unroll
            for (int i = 0; i < 8; ++i)
                #pragma unroll
                for (int j = 0; j < 8; ++j)
                    acc[i][j] = fmaf(ax[i], ay[j], acc[i][j]);
        }
    }

    __syncthreads();
    float* cs = smem;
    #pragma unroll
    for (int i = 0; i < 8; ++i)
        #pragma unroll
        for (int j = 0; j < 8; ++j)
            cs[(ty * 8 + i) * 130 + tx * 8 + j] = (1.0f - acc[i][j]) * INV_LN2;
    __syncthreads();

    float* sk = skew + (size_t)b * (NDIAG * TLEN);
    const int wv = tid >> 6, l = tid & 63;
    for (int dd = wv; dd < 255; dd += 4) {
        int lo = max(0, dd - 127), hi = min(127, dd);
        size_t base = (size_t)(r0 + c0 + dd) * TLEN + r0;
        for (int rb = lo; rb <= hi; rb += 64) {
            int rl = rb + l;
            if (rl <= hi) sk[base + rl] = cs[rl * 129 + dd];   // rl*130 + (dd-rl)
        }
    }
}

// ----------------------------------------------------------------- DTW DP
// 4 waves per batch (256 threads). Wave w owns rows [w*128, w*128+128),
// lane t owns rows r0 = w*128 + 2t + {0,1}. A_d[r] = R(r+1, d-1-r... ) with
// A_d[r] = R(r+1, d-r-1); diag d=k-2 processed at step k.
// Per step: ONE intra-wave shfl + ONE cross-wave float via double-buffered LDS
// + ONE __syncthreads. LDS read consumed only next step -> latency hidden.
// Softmin: e = 1 + 2^(m-mid) + 2^(m-max)  (min term is exactly 1) — 3 trans/cell.

#define SOFTMIN(dg, left, up, cq, jm1, dst)                                    \
  {                                                                            \
    float m_   = fminf(fminf((dg), (left)), (up));                             \
    float mid_ = __builtin_amdgcn_fmed3f((dg), (left), (up));                  \
    float mx_  = fmaxf(fmaxf((dg), (left)), (up));                             \
    float e_   = 1.0f + __builtin_amdgcn_exp2f(m_ - mid_)                      \
                      + __builtin_amdgcn_exp2f(m_ - mx_);                      \
    float v_   = (cq) + m_ - __builtin_amdgcn_logf(e_);                        \
    (dst) = ((unsigned)(jm1) < 512u) ? v_ : vBig;                              \
  }

#define DP_STEP4(CC, PN, PO, PAR)                                              \
  {                                                                            \
    float sh_cur = __shfl_up(PN[1], 1);                                        \
    SOFTMIN(PO[0], PN[1], PN[0], CC.y, vb - 1, PO[1]);     /* q=1 */           \
    if (lt == 63) bnd[PAR][w + 1] = PO[1];                                     \
    __syncthreads();                                                           \
    float nb = bnd[PAR][w];                                                    \
    float up0 = lane0 ? bd_up : sh_cur;                                        \
    float dg0 = lane0 ? bd_dg : sh_prev;                                       \
    SOFTMIN(dg0, PN[0], up0, CC.x, vb, PO[0]);             /* q=0 */           \
    bd_dg = bd_up; bd_up = nb;                                                 \
    sh_prev = sh_cur;                                                          \
    vb += 1;                                                                   \
  }

__global__ __launch_bounds__(256) void sdtw_dp(const float* __restrict__ skew,
                                               float* __restrict__ out) {
    const int b  = blockIdx.x;
    const int w  = threadIdx.x >> 6;
    const int lt = threadIdx.x & 63;
    const bool lane0 = (lt == 0);
    const int r0 = w * 128 + lt * 2;
    const float* skb = skew + (size_t)b * (NDIAG * TLEN) + r0;

    __shared__ float bnd[2][8];
    if (threadIdx.x < 16) ((float*)bnd)[threadIdx.x] = BIGV;

    float P[2], Q[2];
    P[0] = P[1] = Q[0] = Q[1] = BIGV;
    float vBig    = BIGV;
    float sh_prev = BIGV;
    float bd_up   = BIGV;
    float bd_dg   = (w == 0) ? 0.0f : BIGV;   // R(0,0)=0 enters at k=2 (wave0 lane0)
    int   vb      = -r0;                       // (k-2) - r0 at k=2

    __syncthreads();

    // prefetch depth 4 (float2 per lane per diagonal)
    float2 c0 = *(const float2*)(skb + 0 * TLEN);
    float2 c1 = *(const float2*)(skb + 1 * TLEN);
    float2 c2 = *(const float2*)(skb + 2 * TLEN);
    float2 c3 = *(const float2*)(skb + 3 * TLEN);

    // 256 groups x 4 steps: k = 2..1025 (k=1025 is a harmless dummy;
    // the answer lands in Q at k=1024).
    for (int g = 0; g < 256; ++g) {
        int kl = g * 4 + 4;

        DP_STEP4(c0, P, Q, 0);
        c0 = *(const float2*)(skb + (size_t)min(kl + 0, NDIAG - 1) * TLEN);

        DP_STEP4(c1, Q, P, 1);
        c1 = *(const float2*)(skb + (size_t)min(kl + 1, NDIAG - 1) * TLEN);

        DP_STEP4(c2, P, Q, 0);
        c2 = *(const float2*)(skb + (size_t)min(kl + 2, NDIAG - 1) * TLEN);

        DP_STEP4(c3, Q, P, 1);
        c3 = *(const float2*)(skb + (size_t)min(kl + 3, NDIAG - 1) * TLEN);
    }

    if (w == 3 && lt == 63) out[b] = Q[1] * LN2;   // R'(512,512) * ln2
}

// ---------------------------------------------------------------- launcher
extern "C" void kernel_launch(void* const* d_in, const int* in_sizes, int n_in,
                              void* d_out, int out_size, void* d_ws, size_t ws_size,
                              hipStream_t stream) {
    const float* x = (const float*)d_in[0];
    const float* y = (const float*)d_in[1];
    float* outp = (float*)d_out;

    float* xn   = (float*)d_ws;
    float* yn   = xn + (size_t)BT * TLEN * DF;
    float* skew = yn + (size_t)BT * TLEN * DF;

    sdtw_norm<<<dim3(BT * TLEN / 4), dim3(256), 0, stream>>>(x, xn);
    sdtw_norm<<<dim3(BT * TLEN / 4), dim3(256), 0, stream>>>(y, yn);
    sdtw_gemm_skew<<<dim3(4, 4, BT), dim3(256), 0, stream>>>(xn, yn, skew);
    sdtw_dp<<<dim3(BT), dim3(256), 0, stream>>>(skew, outp);
}

// Round 4
// 204.735 us; speedup vs baseline: 3.5476x; 1.2540x over previous
//
#include <hip/hip_runtime.h>
#include <hip/hip_bf16.h>
#include <cstdint>

// Problem: B=32, T1=T2=512, D=128, gamma=1.0
// out[b] = softDTW( 1 - cos_sim(x[b], y[b]) )
//
// ws layout (floats):
//   xn   : 32*512*128           =  2,097,152
//   yn   : 32*512*128           =  2,097,152
//   skew : 32*1023*512          = 16,760,832   (cost/ln2 in anti-diagonal layout)

#define BT      32
#define TLEN    512
#define DF      128
#define NDIAG   1023          // kd = 0..1022  (kd = i-1 + j-1)
#define BIGV    1e30f
#define INV_LN2 1.44269504088896340f
#define LN2     0.69314718055994531f

// ---------------------------------------------------------------- normalize
__global__ __launch_bounds__(256) void sdtw_norm(const float* __restrict__ in,
                                                 float* __restrict__ out) {
    int row = blockIdx.x * 4 + (threadIdx.x >> 6);
    int t   = threadIdx.x & 63;
    const float2* ip = reinterpret_cast<const float2*>(in + (size_t)row * DF);
    float2 v = ip[t];
    float s = v.x * v.x + v.y * v.y;
    #pragma unroll
    for (int o = 32; o; o >>= 1) s += __shfl_xor(s, o);
    float scale = 1.0f / fmaxf(sqrtf(s), 1e-12f);
    float2 w; w.x = v.x * scale; w.y = v.y * scale;
    reinterpret_cast<float2*>(out + (size_t)row * DF)[t] = w;
}

// ------------------------------------------------- cosine-dist GEMM -> skew
#define KC   32
#define SPAD 132

__global__ __launch_bounds__(256) void sdtw_gemm_skew(const float* __restrict__ xn,
                                                      const float* __restrict__ yn,
                                                      float* __restrict__ skew) {
    __shared__ float smem[16640];
    float* xs = smem;                        // [KC][SPAD] transposed: xs[k][row]
    float* ys = smem + KC * SPAD;

    const int b  = blockIdx.z;
    const int r0 = blockIdx.y * 128;
    const int c0 = blockIdx.x * 128;
    const int tid = threadIdx.x;
    const int tx = tid & 15, ty = tid >> 4;

    const float* xb = xn + ((size_t)b * TLEN + r0) * DF;
    const float* yb = yn + ((size_t)b * TLEN + c0) * DF;

    float acc[8][8];
    #pragma unroll
    for (int i = 0; i < 8; ++i)
        #pragma unroll
        for (int j = 0; j < 8; ++j) acc[i][j] = 0.0f;

    for (int kb = 0; kb < DF; kb += KC) {
        __syncthreads();
        #pragma unroll
        for (int i = 0; i < 4; ++i) {
            int g   = tid + i * 256;
            int row = g >> 3;
            int kq  = g & 7;
            float4 vx = *reinterpret_cast<const float4*>(xb + (size_t)row * DF + kb + kq * 4);
            float4 vy = *reinterpret_cast<const float4*>(yb + (size_t)row * DF + kb + kq * 4);
            xs[(kq * 4 + 0) * SPAD + row] = vx.x;
            xs[(kq * 4 + 1) * SPAD + row] = vx.y;
            xs[(kq * 4 + 2) * SPAD + row] = vx.z;
            xs[(kq * 4 + 3) * SPAD + row] = vx.w;
            ys[(kq * 4 + 0) * SPAD + row] = vy.x;
            ys[(kq * 4 + 1) * SPAD + row] = vy.y;
            ys[(kq * 4 + 2) * SPAD + row] = vy.z;
            ys[(kq * 4 + 3) * SPAD + row] = vy.w;
        }
        __syncthreads();
        #pragma unroll
        for (int k = 0; k < KC; ++k) {
            float ax[8], ay[8];
            *reinterpret_cast<float4*>(&ax[0]) = *reinterpret_cast<const float4*>(&xs[k * SPAD + ty * 8]);
            *reinterpret_cast<float4*>(&ax[4]) = *reinterpret_cast<const float4*>(&xs[k * SPAD + ty * 8 + 4]);
            *reinterpret_cast<float4*>(&ay[0]) = *reinterpret_cast<const float4*>(&ys[k * SPAD + tx * 8]);
            *reinterpret_cast<float4*>(&ay[4]) = *reinterpret_cast<const float4*>(&ys[k * SPAD + tx * 8 + 4]);
            #pragma unroll
            for (int i = 0; i < 8; ++i)
                #pragma unroll
                for (int j = 0; j < 8; ++j)
                    acc[i][j] = fmaf(ax[i], ay[j], acc[i][j]);
        }
    }

    __syncthreads();
    float* cs = smem;
    #pragma unroll
    for (int i = 0; i < 8; ++i)
        #pragma unroll
        for (int j = 0; j < 8; ++j)
            cs[(ty * 8 + i) * 130 + tx * 8 + j] = (1.0f - acc[i][j]) * INV_LN2;
    __syncthreads();

    float* sk = skew + (size_t)b * (NDIAG * TLEN);
    const int wv = tid >> 6, l = tid & 63;
    for (int dd = wv; dd < 255; dd += 4) {
        int lo = max(0, dd - 127), hi = min(127, dd);
        size_t base = (size_t)(r0 + c0 + dd) * TLEN + r0;
        for (int rb = lo; rb <= hi; rb += 64) {
            int rl = rb + l;
            if (rl <= hi) sk[base + rl] = cs[rl * 129 + dd];   // rl*130 + (dd-rl)
        }
    }
}

// ----------------------------------------------------------------- DTW DP
// Staggered wavefront: 4 waves per batch; wave w owns rows [w*128, w*128+128)
// (lane t -> rows w*128 + 2t + {0,1}), and processes diag kd at global phase
// p = kd + 16*w. Cross-wave boundary values flow through a 32-slot circular
// LDS buffer per wave-pair; producer runs 16 phases ahead, so ONE
// __syncthreads per 16-phase segment guarantees visibility. Within a segment,
// read slots (kd..kd+15 mod 32) and producer write slots (kd+16..kd+31 mod 32)
// are disjoint -> race-free. Inactive phases (kd<0 or kd>1022) compute junk
// that the validity mask turns into BIGV -> branch-free. 67*16 = 1072 phases;
// wave 3 computes kd=1022 at p=1070 (writes Q), p=1071 writes P -> answer
// survives in Q[1] of (w=3, lane 63).

#define SOFTMIN(dg, left, up, cq, jm1, dst)                                    \
  {                                                                            \
    float m_   = fminf(fminf((dg), (left)), (up));                             \
    float mid_ = __builtin_amdgcn_fmed3f((dg), (left), (up));                  \
    float mx_  = fmaxf(fmaxf((dg), (left)), (up));                             \
    float e_   = 1.0f + __builtin_amdgcn_exp2f(m_ - mid_)                      \
                      + __builtin_amdgcn_exp2f(m_ - mx_);                      \
    float v_   = (cq) + m_ - __builtin_amdgcn_logf(e_);                        \
    (dst) = ((unsigned)(jm1) < 512u) ? v_ : vBig;                              \
  }

#define DP_PHASE(CC, PN, PO)                                                   \
  {                                                                            \
    float sh_cur = __shfl_up(PN[1], 1);                                        \
    SOFTMIN(PO[0], PN[1], PN[0], CC.y, vb - 1, PO[1]);        /* q=1 */        \
    if (lt == 63) bnd[w + 1][kd & 31] = PO[1];                                 \
    float nb  = bnd[w][kd & 31];                 /* diag kd, consumed next */  \
    float up0 = lane0 ? bd_up : sh_cur;                                        \
    float dg0 = lane0 ? bd_dg : sh_prev;                                       \
    SOFTMIN(dg0, PN[0], up0, CC.x, vb, PO[0]);                /* q=0 */        \
    bd_dg = bd_up; bd_up = nb;                                                 \
    sh_prev = sh_cur;                                                          \
    int kcl = kd + 4;                                                          \
    kcl = kcl < 0 ? 0 : (kcl > NDIAG - 1 ? NDIAG - 1 : kcl);                   \
    CC = *(const float2*)(skb + (size_t)kcl * TLEN);                           \
    ++kd; ++vb;                                                                \
  }

__global__ __launch_bounds__(256) void sdtw_dp(const float* __restrict__ skew,
                                               float* __restrict__ out) {
    const int b  = blockIdx.x;
    const int w  = threadIdx.x >> 6;
    const int lt = threadIdx.x & 63;
    const bool lane0 = (lt == 0);
    const int r0 = w * 128 + lt * 2;
    const float* skb = skew + (size_t)b * (NDIAG * TLEN) + r0;

    __shared__ float bnd[5][32];                 // [consumer wave][slot]
    if (threadIdx.x < 160) ((float*)bnd)[threadIdx.x] = BIGV;

    float P[2], Q[2];
    P[0] = P[1] = Q[0] = Q[1] = BIGV;
    float vBig    = BIGV;
    float sh_prev = BIGV;
    float bd_up   = BIGV;
    float bd_dg   = (w == 0) ? 0.0f : BIGV;      // R(0,0)=0 enters at kd=0, wave0
    int   kd      = -16 * w;                     // diag index at phase 0
    int   vb      = -144 * w - 2 * lt;           // kd - r0

    __syncthreads();

    // prefetch depth 4 (clamped; junk values are masked by validity)
    float2 c0, c1, c2, c3;
    {
        int k0 = kd < 0 ? 0 : kd;
        int k1 = kd + 1 < 0 ? 0 : kd + 1;
        int k2 = kd + 2 < 0 ? 0 : kd + 2;
        int k3 = kd + 3 < 0 ? 0 : kd + 3;
        c0 = *(const float2*)(skb + (size_t)k0 * TLEN);
        c1 = *(const float2*)(skb + (size_t)k1 * TLEN);
        c2 = *(const float2*)(skb + (size_t)k2 * TLEN);
        c3 = *(const float2*)(skb + (size_t)k3 * TLEN);
    }

    for (int seg = 0; seg < 67; ++seg) {
        DP_PHASE(c0, P, Q);   // s=0  (even phase -> writes Q)
        DP_PHASE(c1, Q, P);   // s=1
        DP_PHASE(c2, P, Q);   // s=2
        DP_PHASE(c3, Q, P);   // s=3
        DP_PHASE(c0, P, Q);   // s=4
        DP_PHASE(c1, Q, P);   // s=5
        DP_PHASE(c2, P, Q);   // s=6
        DP_PHASE(c3, Q, P);   // s=7
        DP_PHASE(c0, P, Q);   // s=8
        DP_PHASE(c1, Q, P);   // s=9
        DP_PHASE(c2, P, Q);   // s=10
        DP_PHASE(c3, Q, P);   // s=11
        DP_PHASE(c0, P, Q);   // s=12
        DP_PHASE(c1, Q, P);   // s=13
        DP_PHASE(c2, P, Q);   // s=14
        DP_PHASE(c3, Q, P);   // s=15
        __syncthreads();
    }

    if (w == 3 && lt == 63) out[b] = Q[1] * LN2;   // R'(512,512) * ln2
}

// ---------------------------------------------------------------- launcher
extern "C" void kernel_launch(void* const* d_in, const int* in_sizes, int n_in,
                              void* d_out, int out_size, void* d_ws, size_t ws_size,
                              hipStream_t stream) {
    const float* x = (const float*)d_in[0];
    const float* y = (const float*)d_in[1];
    float* outp = (float*)d_out;

    float* xn   = (float*)d_ws;
    float* yn   = xn + (size_t)BT * TLEN * DF;
    float* skew = yn + (size_t)BT * TLEN * DF;

    sdtw_norm<<<dim3(BT * TLEN / 4), dim3(256), 0, stream>>>(x, xn);
    sdtw_norm<<<dim3(BT * TLEN / 4), dim3(256), 0, stream>>>(y, yn);
    sdtw_gemm_skew<<<dim3(4, 4, BT), dim3(256), 0, stream>>>(xn, yn, skew);
    sdtw_dp<<<dim3(BT), dim3(256), 0, stream>>>(skew, outp);
}

// Round 5
// 204.567 us; speedup vs baseline: 3.5505x; 1.0008x over previous
//
#include <hip/hip_runtime.h>
#include <hip/hip_bf16.h>
#include <cstdint>

// Problem: B=32, T1=T2=512, D=128, gamma=1.0
// out[b] = softDTW( 1 - cos_sim(x[b], y[b]) )
//
// ws layout (floats):
//   xn   : 32*512*128           =  2,097,152
//   yn   : 32*512*128           =  2,097,152
//   skew : 32*1023*512          = 16,760,832   (cost/ln2 in anti-diagonal layout)

#define BT      32
#define TLEN    512
#define DF      128
#define NDIAG   1023          // kd = 0..1022  (kd = i-1 + j-1)
#define BIGV    1e30f
#define INV_LN2 1.44269504088896340f
#define LN2     0.69314718055994531f

// ---------------------------------------------------------------- normalize
__global__ __launch_bounds__(256) void sdtw_norm(const float* __restrict__ in,
                                                 float* __restrict__ out) {
    int row = blockIdx.x * 4 + (threadIdx.x >> 6);
    int t   = threadIdx.x & 63;
    const float2* ip = reinterpret_cast<const float2*>(in + (size_t)row * DF);
    float2 v = ip[t];
    float s = v.x * v.x + v.y * v.y;
    #pragma unroll
    for (int o = 32; o; o >>= 1) s += __shfl_xor(s, o);
    float scale = 1.0f / fmaxf(sqrtf(s), 1e-12f);
    float2 w; w.x = v.x * scale; w.y = v.y * scale;
    reinterpret_cast<float2*>(out + (size_t)row * DF)[t] = w;
}

// ------------------------------------------------- cosine-dist GEMM -> skew
#define KC   32
#define SPAD 132

__global__ __launch_bounds__(256) void sdtw_gemm_skew(const float* __restrict__ xn,
                                                      const float* __restrict__ yn,
                                                      float* __restrict__ skew) {
    __shared__ float smem[16640];
    float* xs = smem;                        // [KC][SPAD] transposed: xs[k][row]
    float* ys = smem + KC * SPAD;

    const int b  = blockIdx.z;
    const int r0 = blockIdx.y * 128;
    const int c0 = blockIdx.x * 128;
    const int tid = threadIdx.x;
    const int tx = tid & 15, ty = tid >> 4;

    const float* xb = xn + ((size_t)b * TLEN + r0) * DF;
    const float* yb = yn + ((size_t)b * TLEN + c0) * DF;

    float acc[8][8];
    #pragma unroll
    for (int i = 0; i < 8; ++i)
        #pragma unroll
        for (int j = 0; j < 8; ++j) acc[i][j] = 0.0f;

    for (int kb = 0; kb < DF; kb += KC) {
        __syncthreads();
        #pragma unroll
        for (int i = 0; i < 4; ++i) {
            int g   = tid + i * 256;
            int row = g >> 3;
            int kq  = g & 7;
            float4 vx = *reinterpret_cast<const float4*>(xb + (size_t)row * DF + kb + kq * 4);
            float4 vy = *reinterpret_cast<const float4*>(yb + (size_t)row * DF + kb + kq * 4);
            xs[(kq * 4 + 0) * SPAD + row] = vx.x;
            xs[(kq * 4 + 1) * SPAD + row] = vx.y;
            xs[(kq * 4 + 2) * SPAD + row] = vx.z;
            xs[(kq * 4 + 3) * SPAD + row] = vx.w;
            ys[(kq * 4 + 0) * SPAD + row] = vy.x;
            ys[(kq * 4 + 1) * SPAD + row] = vy.y;
            ys[(kq * 4 + 2) * SPAD + row] = vy.z;
            ys[(kq * 4 + 3) * SPAD + row] = vy.w;
        }
        __syncthreads();
        #pragma unroll
        for (int k = 0; k < KC; ++k) {
            float ax[8], ay[8];
            *reinterpret_cast<float4*>(&ax[0]) = *reinterpret_cast<const float4*>(&xs[k * SPAD + ty * 8]);
            *reinterpret_cast<float4*>(&ax[4]) = *reinterpret_cast<const float4*>(&xs[k * SPAD + ty * 8 + 4]);
            *reinterpret_cast<float4*>(&ay[0]) = *reinterpret_cast<const float4*>(&ys[k * SPAD + tx * 8]);
            *reinterpret_cast<float4*>(&ay[4]) = *reinterpret_cast<const float4*>(&ys[k * SPAD + tx * 8 + 4]);
            #pragma unroll
            for (int i = 0; i < 8; ++i)
                #pragma unroll
                for (int j = 0; j < 8; ++j)
                    acc[i][j] = fmaf(ax[i], ay[j], acc[i][j]);
        }
    }

    __syncthreads();
    float* cs = smem;
    #pragma unroll
    for (int i = 0; i < 8; ++i)
        #pragma unroll
        for (int j = 0; j < 8; ++j)
            cs[(ty * 8 + i) * 130 + tx * 8 + j] = (1.0f - acc[i][j]) * INV_LN2;
    __syncthreads();

    float* sk = skew + (size_t)b * (NDIAG * TLEN);
    const int wv = tid >> 6, l = tid & 63;
    for (int dd = wv; dd < 255; dd += 4) {
        int lo = max(0, dd - 127), hi = min(127, dd);
        size_t base = (size_t)(r0 + c0 + dd) * TLEN + r0;
        for (int rb = lo; rb <= hi; rb += 64) {
            int rl = rb + l;
            if (rl <= hi) sk[base + rl] = cs[rl * 129 + dd];   // rl*130 + (dd-rl)
        }
    }
}

// ----------------------------------------------------------------- DTW DP
// 8 waves per batch (512 threads), lane owns ONE row r = tid. Staggered
// wavefront: wave w processes diag kd at phase p = kd + 16w. Value at (kd,r)
// = R(r+1, kd-r+1). Per phase per lane: 1 softmin, 1 shfl_up; lane-0
// boundary values flow via float4-batched circular LDS quads (1 ds_read +
// 1 ds_write per 4 phases). One __syncthreads per 16-phase segment; producer
// is 16 phases ahead -> every consumer read is barrier-separated from its
// producing write (read phases ≡{0,4,8,12} mod 16 read quads written 13
// phases earlier ≡{3,7,11,15} of the PREVIOUS segment), and within a segment
// consumer-read quads and producer-written quads are disjoint mod 8.
// Invalid cells (kd-r ∉ [0,512)) masked to BIGV -> fill/overrun phases are
// branch-free junk. 71 segments * 16 = 1136 phases; wave 7 computes kd=1022
// at phase 1134 (writes Q); phase 1135 writes P -> answer in Q of tid 511.

__device__ __forceinline__ int clampi(int v) {
    return v < 0 ? 0 : (v > NDIAG - 1 ? NDIAG - 1 : v);
}

#define DP_COMMON(s, CC, PN, PO, LOADEXPR)                                     \
  {                                                                            \
    float sh_cur = __shfl_up(PN, 1);                                           \
    if (((s) & 3) == 0) nq = bnd4[w][(kd >> 2) & 7];                           \
    float up_ = lane0 ? bd_up : sh_cur;                                        \
    float dg_ = lane0 ? bd_dg : sh_prev;                                       \
    float m_   = fminf(fminf(dg_, PN), up_);                                   \
    float mid_ = __builtin_amdgcn_fmed3f(dg_, PN, up_);                        \
    float mx_  = fmaxf(fmaxf(dg_, PN), up_);                                   \
    float e_   = 1.0f + __builtin_amdgcn_exp2f(m_ - mid_)                      \
                      + __builtin_amdgcn_exp2f(m_ - mx_);                      \
    float v_   = CC + m_ - __builtin_amdgcn_logf(e_);                          \
    PO = ((unsigned)vb < 512u) ? v_ : vBig;                                    \
    if (((s) & 3) == 0) bq.x = PO;                                             \
    if (((s) & 3) == 1) bq.y = PO;                                             \
    if (((s) & 3) == 2) bq.z = PO;                                             \
    if (((s) & 3) == 3) { bq.w = PO;                                           \
      if (lt == 63) bnd4[w + 1][(kd >> 2) & 7] = bq; }                         \
    bd_dg = bd_up;                                                             \
    bd_up = ((s) & 3) == 0 ? nq.x : ((s) & 3) == 1 ? nq.y                      \
          : ((s) & 3) == 2 ? nq.z : nq.w;                                      \
    sh_prev = sh_cur;                                                          \
    CC = (LOADEXPR);                                                           \
    ++kd; ++vb;                                                                \
  }

#define DP_F(s, CC, PN, PO) DP_COMMON(s, CC, PN, PO, skb[(size_t)(kd + 8) * TLEN])
#define DP_C(s, CC, PN, PO) DP_COMMON(s, CC, PN, PO, skb[(size_t)clampi(kd + 8) * TLEN])

#define SEG16(MAC)                                                             \
    MAC(0,  c0, P, Q) MAC(1,  c1, Q, P) MAC(2,  c2, P, Q) MAC(3,  c3, Q, P)    \
    MAC(4,  c4, P, Q) MAC(5,  c5, Q, P) MAC(6,  c6, P, Q) MAC(7,  c7, Q, P)    \
    MAC(8,  c0, P, Q) MAC(9,  c1, Q, P) MAC(10, c2, P, Q) MAC(11, c3, Q, P)    \
    MAC(12, c4, P, Q) MAC(13, c5, Q, P) MAC(14, c6, P, Q) MAC(15, c7, Q, P)

__global__ __launch_bounds__(512) void sdtw_dp(const float* __restrict__ skew,
                                               float* __restrict__ out) {
    const int b   = blockIdx.x;
    const int tid = threadIdx.x;
    const int w   = tid >> 6;
    const int lt  = tid & 63;
    const bool lane0 = (lt == 0);
    const float* skb = skew + (size_t)b * (NDIAG * TLEN) + tid;   // row r = tid

    __shared__ float4 bnd4[9][8];                // [consumer wave][quad slot]
    if (tid < 288) ((float*)bnd4)[tid] = BIGV;

    float P = BIGV, Q = BIGV;
    float vBig    = BIGV;
    float sh_prev = BIGV;
    float bd_up   = BIGV;
    float bd_dg   = (w == 0) ? 0.0f : BIGV;      // R(0,0)=0 enters at kd=0, wave0
    int   kd      = -16 * w;                     // diag index at phase 0
    int   vb      = kd - tid;                    // j-1 = kd - r
    float4 nq = make_float4(BIGV, BIGV, BIGV, BIGV);
    float4 bq = make_float4(BIGV, BIGV, BIGV, BIGV);

    __syncthreads();

    // prefetch depth 8 (clamped; junk masked by validity)
    float c0 = skb[(size_t)clampi(kd + 0) * TLEN];
    float c1 = skb[(size_t)clampi(kd + 1) * TLEN];
    float c2 = skb[(size_t)clampi(kd + 2) * TLEN];
    float c3 = skb[(size_t)clampi(kd + 3) * TLEN];
    float c4 = skb[(size_t)clampi(kd + 4) * TLEN];
    float c5 = skb[(size_t)clampi(kd + 5) * TLEN];
    float c6 = skb[(size_t)clampi(kd + 6) * TLEN];
    float c7 = skb[(size_t)clampi(kd + 7) * TLEN];

    for (int seg = 0; seg < 7; ++seg)  { SEG16(DP_C) __syncthreads(); }  // head (fill)
    for (int seg = 0; seg < 56; ++seg) { SEG16(DP_F) __syncthreads(); }  // steady
    for (int seg = 0; seg < 8; ++seg)  { SEG16(DP_C) __syncthreads(); }  // tail (drain)

    if (tid == 511) out[b] = Q * LN2;            // R'(512,512) * ln2
}

// ---------------------------------------------------------------- launcher
extern "C" void kernel_launch(void* const* d_in, const int* in_sizes, int n_in,
                              void* d_out, int out_size, void* d_ws, size_t ws_size,
                              hipStream_t stream) {
    const float* x = (const float*)d_in[0];
    const float* y = (const float*)d_in[1];
    float* outp = (float*)d_out;

    float* xn   = (float*)d_ws;
    float* yn   = xn + (size_t)BT * TLEN * DF;
    float* skew = yn + (size_t)BT * TLEN * DF;

    sdtw_norm<<<dim3(BT * TLEN / 4), dim3(256), 0, stream>>>(x, xn);
    sdtw_norm<<<dim3(BT * TLEN / 4), dim3(256), 0, stream>>>(y, yn);
    sdtw_gemm_skew<<<dim3(4, 4, BT), dim3(256), 0, stream>>>(xn, yn, skew);
    sdtw_dp<<<dim3(BT), dim3(512), 0, stream>>>(skew, outp);
}

// Round 6
// 187.968 us; speedup vs baseline: 3.8641x; 1.0883x over previous
//
#include <hip/hip_runtime.h>
#include <hip/hip_bf16.h>
#include <cstdint>

// Problem: B=32, T1=T2=512, D=128, gamma=1.0
// out[b] = softDTW( 1 - cos_sim(x[b], y[b]) )
//
// ws layout (floats):
//   invnx : 32*512            =     16,384
//   invny : 32*512            =     16,384
//   skew  : 32*1023*512       = 16,760,832   (cost/ln2 in anti-diagonal layout)

#define BT      32
#define TLEN    512
#define DF      128
#define NDIAG   1023          // kd = 0..1022  (kd = i-1 + j-1)
#define BIGV    1e30f
#define INV_LN2 1.44269504088896340f
#define LN2     0.69314718055994531f

// ------------------------------------------------------------- inverse norms
__global__ __launch_bounds__(256) void sdtw_invnorm(const float* __restrict__ in,
                                                    float* __restrict__ outv) {
    int row = blockIdx.x * 4 + (threadIdx.x >> 6);
    int t   = threadIdx.x & 63;
    const float2* ip = reinterpret_cast<const float2*>(in + (size_t)row * DF);
    float2 v = ip[t];
    float s = v.x * v.x + v.y * v.y;
    #pragma unroll
    for (int o = 32; o; o >>= 1) s += __shfl_xor(s, o);
    if (t == 0) outv[row] = 1.0f / fmaxf(sqrtf(s), 1e-12f);
}

// ------------------------------------------------- cosine-dist GEMM -> skew
// reads RAW x,y; scales by inv-norms in the epilogue.
#define KC   32
#define SPAD 132

__global__ __launch_bounds__(256) void sdtw_gemm_skew(const float* __restrict__ x,
                                                      const float* __restrict__ y,
                                                      const float* __restrict__ invnx,
                                                      const float* __restrict__ invny,
                                                      float* __restrict__ skew) {
    __shared__ float smem[16640];
    float* xs = smem;                        // [KC][SPAD] transposed: xs[k][row]
    float* ys = smem + KC * SPAD;

    const int b  = blockIdx.z;
    const int r0 = blockIdx.y * 128;
    const int c0 = blockIdx.x * 128;
    const int tid = threadIdx.x;
    const int tx = tid & 15, ty = tid >> 4;

    const float* xb = x + ((size_t)b * TLEN + r0) * DF;
    const float* yb = y + ((size_t)b * TLEN + c0) * DF;

    float acc[8][8];
    #pragma unroll
    for (int i = 0; i < 8; ++i)
        #pragma unroll
        for (int j = 0; j < 8; ++j) acc[i][j] = 0.0f;

    for (int kb = 0; kb < DF; kb += KC) {
        __syncthreads();
        #pragma unroll
        for (int i = 0; i < 4; ++i) {
            int g   = tid + i * 256;
            int row = g >> 3;
            int kq  = g & 7;
            float4 vx = *reinterpret_cast<const float4*>(xb + (size_t)row * DF + kb + kq * 4);
            float4 vy = *reinterpret_cast<const float4*>(yb + (size_t)row * DF + kb + kq * 4);
            xs[(kq * 4 + 0) * SPAD + row] = vx.x;
            xs[(kq * 4 + 1) * SPAD + row] = vx.y;
            xs[(kq * 4 + 2) * SPAD + row] = vx.z;
            xs[(kq * 4 + 3) * SPAD + row] = vx.w;
            ys[(kq * 4 + 0) * SPAD + row] = vy.x;
            ys[(kq * 4 + 1) * SPAD + row] = vy.y;
            ys[(kq * 4 + 2) * SPAD + row] = vy.z;
            ys[(kq * 4 + 3) * SPAD + row] = vy.w;
        }
        __syncthreads();
        #pragma unroll
        for (int k = 0; k < KC; ++k) {
            float ax[8], ay[8];
            *reinterpret_cast<float4*>(&ax[0]) = *reinterpret_cast<const float4*>(&xs[k * SPAD + ty * 8]);
            *reinterpret_cast<float4*>(&ax[4]) = *reinterpret_cast<const float4*>(&xs[k * SPAD + ty * 8 + 4]);
            *reinterpret_cast<float4*>(&ay[0]) = *reinterpret_cast<const float4*>(&ys[k * SPAD + tx * 8]);
            *reinterpret_cast<float4*>(&ay[4]) = *reinterpret_cast<const float4*>(&ys[k * SPAD + tx * 8 + 4]);
            #pragma unroll
            for (int i = 0; i < 8; ++i)
                #pragma unroll
                for (int j = 0; j < 8; ++j)
                    acc[i][j] = fmaf(ax[i], ay[j], acc[i][j]);
        }
    }

    // epilogue: (1 - dot*invnx*invny)/ln2 into LDS tile [128][130]
    float rn[8], cn[8];
    #pragma unroll
    for (int i = 0; i < 8; ++i) rn[i] = invnx[b * TLEN + r0 + ty * 8 + i];
    #pragma unroll
    for (int j = 0; j < 8; ++j) cn[j] = invny[b * TLEN + c0 + tx * 8 + j];

    __syncthreads();
    float* cs = smem;
    #pragma unroll
    for (int i = 0; i < 8; ++i)
        #pragma unroll
        for (int j = 0; j < 8; ++j)
            cs[(ty * 8 + i) * 130 + tx * 8 + j] =
                (1.0f - acc[i][j] * rn[i] * cn[j]) * INV_LN2;
    __syncthreads();

    float* sk = skew + (size_t)b * (NDIAG * TLEN);
    const int wv = tid >> 6, l = tid & 63;
    for (int dd = wv; dd < 255; dd += 4) {
        int lo = max(0, dd - 127), hi = min(127, dd);
        size_t base = (size_t)(r0 + c0 + dd) * TLEN + r0;
        for (int rb = lo; rb <= hi; rb += 64) {
            int rl = rb + l;
            if (rl <= hi) sk[base + rl] = cs[rl * 129 + dd];   // rl*130 + (dd-rl)
        }
    }
}

// ----------------------------------------------------------------- DTW DP
// 8 waves per batch (512 threads), lane owns row r = tid; wave w processes
// diag kd at phase p = kd + 16w. One __syncthreads per 16-phase segment.
// NEW: per-segment mode per wave (wave-uniform branch, no divergence):
//   JUNK     (s <= 5w-2 or s >= 5w+36): all cells invalid -> skip compute &
//            loads; lane63 still writes BIGV boundary quads (same slots the
//            active cadence would write -> R4 race-freedom carries over).
//   PARTIAL  (s in [5w-1, 5w+3] U [5w+32, 5w+35]): masked + clamped loads.
//            s == 5w-1 is an all-invalid warm-up that rebuilds nq/bd state
//            from wave w-1's quads and re-primes the cost prefetch.
//   INTERIOR (s in [5w+4, 5w+31]): all cells valid -> mask & clamp removed.
// Validity: cell (kd,r) valid iff vb = kd-r in [0,512). Interior bounds:
// kd0 >= 64w+63 and kd0+15 <= 64w+496+15 (=> vb in [0,511] for all lanes).

__device__ __forceinline__ int clampi(int v) {
    return v < 0 ? 0 : (v > NDIAG - 1 ? NDIAG - 1 : v);
}

#define PH(s, CC, PN, PO, MASKED, CLAMPED)                                     \
  {                                                                            \
    float sh_cur = __shfl_up(PN, 1);                                           \
    if (((s) & 3) == 0) nq = bnd4[w][(q0 + ((s) >> 2)) & 7];                   \
    float up_ = lane0 ? bd_up : sh_cur;                                        \
    float dg_ = lane0 ? bd_dg : sh_prev;                                       \
    float m_   = fminf(fminf(dg_, PN), up_);                                   \
    float mid_ = __builtin_amdgcn_fmed3f(dg_, PN, up_);                        \
    float mx_  = fmaxf(fmaxf(dg_, PN), up_);                                   \
    float e_   = 1.0f + __builtin_amdgcn_exp2f(m_ - mid_)                      \
                      + __builtin_amdgcn_exp2f(m_ - mx_);                      \
    float v_   = CC + m_ - __builtin_amdgcn_logf(e_);                          \
    PO = (MASKED) ? (((unsigned)(vb0 + (s)) < 512u) ? v_ : vBig) : v_;         \
    if (((s) & 3) == 0) bq.x = PO;                                             \
    if (((s) & 3) == 1) bq.y = PO;                                             \
    if (((s) & 3) == 2) bq.z = PO;                                             \
    if (((s) & 3) == 3) { bq.w = PO;                                           \
      if (lt == 63) bnd4[w + 1][(q0 + ((s) >> 2)) & 7] = bq; }                 \
    bd_dg = bd_up;                                                             \
    bd_up = ((s) & 3) == 0 ? nq.x : ((s) & 3) == 1 ? nq.y                      \
          : ((s) & 3) == 2 ? nq.z : nq.w;                                      \
    sh_prev = sh_cur;                                                          \
    { int kl_ = kd0 + (s) + 8; if (CLAMPED) kl_ = clampi(kl_);                 \
      CC = skb[(size_t)kl_ * TLEN]; }                                          \
  }

#define SEG_BODY(MASKED, CLAMPED)                                              \
    PH(0,  c0, P, Q, MASKED, CLAMPED) PH(1,  c1, Q, P, MASKED, CLAMPED)        \
    PH(2,  c2, P, Q, MASKED, CLAMPED) PH(3,  c3, Q, P, MASKED, CLAMPED)        \
    PH(4,  c4, P, Q, MASKED, CLAMPED) PH(5,  c5, Q, P, MASKED, CLAMPED)        \
    PH(6,  c6, P, Q, MASKED, CLAMPED) PH(7,  c7, Q, P, MASKED, CLAMPED)        \
    PH(8,  c0, P, Q, MASKED, CLAMPED) PH(9,  c1, Q, P, MASKED, CLAMPED)        \
    PH(10, c2, P, Q, MASKED, CLAMPED) PH(11, c3, Q, P, MASKED, CLAMPED)        \
    PH(12, c4, P, Q, MASKED, CLAMPED) PH(13, c5, Q, P, MASKED, CLAMPED)        \
    PH(14, c6, P, Q, MASKED, CLAMPED) PH(15, c7, Q, P, MASKED, CLAMPED)

#define PRIME(K)                                                               \
    c0 = skb[(size_t)clampi((K) + 0) * TLEN];                                  \
    c1 = skb[(size_t)clampi((K) + 1) * TLEN];                                  \
    c2 = skb[(size_t)clampi((K) + 2) * TLEN];                                  \
    c3 = skb[(size_t)clampi((K) + 3) * TLEN];                                  \
    c4 = skb[(size_t)clampi((K) + 4) * TLEN];                                  \
    c5 = skb[(size_t)clampi((K) + 5) * TLEN];                                  \
    c6 = skb[(size_t)clampi((K) + 6) * TLEN];                                  \
    c7 = skb[(size_t)clampi((K) + 7) * TLEN];

__global__ __launch_bounds__(512) void sdtw_dp(const float* __restrict__ skew,
                                               float* __restrict__ out) {
    const int b   = blockIdx.x;
    const int tid = threadIdx.x;
    const int w   = tid >> 6;
    const int lt  = tid & 63;
    const bool lane0 = (lt == 0);
    const float* skb = skew + (size_t)b * (NDIAG * TLEN) + tid;   // row r = tid

    __shared__ float4 bnd4[9][8];                // [consumer wave][quad slot]
    if (tid < 288) ((float*)bnd4)[tid] = BIGV;

    float P = BIGV, Q = BIGV;
    float vBig    = BIGV;
    float sh_prev = BIGV;
    float bd_up   = BIGV;
    float bd_dg   = (w == 0) ? 0.0f : BIGV;      // R(0,0)=0 enters at kd=0, wave0
    float4 nq = make_float4(BIGV, BIGV, BIGV, BIGV);
    float4 bq = make_float4(BIGV, BIGV, BIGV, BIGV);

    __syncthreads();

    float c0, c1, c2, c3, c4, c5, c6, c7;
    PRIME(-16 * w)                               // real prime for w=0; harmless else

    for (int s = 0; s < 71; ++s) {
        const int sw  = s - 5 * w;               // wave-uniform
        const int kd0 = 16 * (s - w);
        const int q0  = (kd0 >> 2) & 7;
        const int vb0 = kd0 - tid;

        if (sw >= -1 && sw <= 35) {
            if (sw == -1) { PRIME(kd0) }         // warm-up: re-prime prefetch
            if (sw >= 4 && sw <= 31) { SEG_BODY(0, 0) }   // interior: no mask/clamp
            else                     { SEG_BODY(1, 1) }   // staircase/warm-up
        } else {
            if (lt == 63) {                      // junk: keep boundary cadence
                float4 bigq = make_float4(BIGV, BIGV, BIGV, BIGV);
                bnd4[w + 1][q0]           = bigq;
                bnd4[w + 1][(q0 + 1) & 7] = bigq;
                bnd4[w + 1][(q0 + 2) & 7] = bigq;
                bnd4[w + 1][(q0 + 3) & 7] = bigq;
            }
        }
        __syncthreads();
    }

    if (tid == 511) out[b] = Q * LN2;            // R'(512,512) * ln2
}

// ---------------------------------------------------------------- launcher
extern "C" void kernel_launch(void* const* d_in, const int* in_sizes, int n_in,
                              void* d_out, int out_size, void* d_ws, size_t ws_size,
                              hipStream_t stream) {
    const float* x = (const float*)d_in[0];
    const float* y = (const float*)d_in[1];
    float* outp = (float*)d_out;

    float* invnx = (float*)d_ws;                          //  16,384 floats
    float* invny = invnx + (size_t)BT * TLEN;             //  16,384 floats
    float* skew  = invny + (size_t)BT * TLEN;             //  16,760,832 floats

    sdtw_invnorm<<<dim3(BT * TLEN / 4), dim3(256), 0, stream>>>(x, invnx);
    sdtw_invnorm<<<dim3(BT * TLEN / 4), dim3(256), 0, stream>>>(y, invny);
    sdtw_gemm_skew<<<dim3(4, 4, BT), dim3(256), 0, stream>>>(x, y, invnx, invny, skew);
    sdtw_dp<<<dim3(BT), dim3(512), 0, stream>>>(skew, outp);
}

// Round 7
// 161.080 us; speedup vs baseline: 4.5091x; 1.1669x over previous
//
#include <hip/hip_runtime.h>
#include <hip/hip_bf16.h>
#include <cstdint>

// Problem: B=32, T1=T2=512, D=128, gamma=1.0
// out[b] = softDTW( 1 - cos_sim(x[b], y[b]) )
//
// ws layout (floats):
//   invnx : 32*512            =     16,384
//   invny : 32*512            =     16,384
//   skew  : 32*1023*512       = 16,760,832   (cost/ln2 in anti-diagonal layout)

#define BT      32
#define TLEN    512
#define DF      128
#define NDIAG   1023          // kd = 0..1022  (kd = i-1 + j-1)
#define BIGV    1e30f
#define INV_LN2 1.44269504088896340f
#define LN2     0.69314718055994531f

// ------------------------------------------------------------- inverse norms
// gridDim.y = 2 : y-index 0 -> x, 1 -> y.
__global__ __launch_bounds__(256) void sdtw_invnorm(const float* __restrict__ x,
                                                    const float* __restrict__ y,
                                                    float* __restrict__ ox,
                                                    float* __restrict__ oy) {
    const float* in  = blockIdx.y ? y : x;
    float*       out = blockIdx.y ? oy : ox;
    int row = blockIdx.x * 4 + (threadIdx.x >> 6);
    int t   = threadIdx.x & 63;
    const float2* ip = reinterpret_cast<const float2*>(in + (size_t)row * DF);
    float2 v = ip[t];
    float s = v.x * v.x + v.y * v.y;
    #pragma unroll
    for (int o = 32; o; o >>= 1) s += __shfl_xor(s, o);
    if (t == 0) out[row] = 1.0f / fmaxf(sqrtf(s), 1e-12f);
}

// ------------------------------------------------- cosine-dist GEMM -> skew
#define KC   32
#define SPAD 132

__global__ __launch_bounds__(256) void sdtw_gemm_skew(const float* __restrict__ x,
                                                      const float* __restrict__ y,
                                                      const float* __restrict__ invnx,
                                                      const float* __restrict__ invny,
                                                      float* __restrict__ skew) {
    __shared__ float smem[16640];
    float* xs = smem;                        // [KC][SPAD] transposed: xs[k][row]
    float* ys = smem + KC * SPAD;

    const int b  = blockIdx.z;
    const int r0 = blockIdx.y * 128;
    const int c0 = blockIdx.x * 128;
    const int tid = threadIdx.x;
    const int tx = tid & 15, ty = tid >> 4;

    const float* xb = x + ((size_t)b * TLEN + r0) * DF;
    const float* yb = y + ((size_t)b * TLEN + c0) * DF;

    float acc[8][8];
    #pragma unroll
    for (int i = 0; i < 8; ++i)
        #pragma unroll
        for (int j = 0; j < 8; ++j) acc[i][j] = 0.0f;

    for (int kb = 0; kb < DF; kb += KC) {
        __syncthreads();
        #pragma unroll
        for (int i = 0; i < 4; ++i) {
            int g   = tid + i * 256;
            int row = g >> 3;
            int kq  = g & 7;
            float4 vx = *reinterpret_cast<const float4*>(xb + (size_t)row * DF + kb + kq * 4);
            float4 vy = *reinterpret_cast<const float4*>(yb + (size_t)row * DF + kb + kq * 4);
            xs[(kq * 4 + 0) * SPAD + row] = vx.x;
            xs[(kq * 4 + 1) * SPAD + row] = vx.y;
            xs[(kq * 4 + 2) * SPAD + row] = vx.z;
            xs[(kq * 4 + 3) * SPAD + row] = vx.w;
            ys[(kq * 4 + 0) * SPAD + row] = vy.x;
            ys[(kq * 4 + 1) * SPAD + row] = vy.y;
            ys[(kq * 4 + 2) * SPAD + row] = vy.z;
            ys[(kq * 4 + 3) * SPAD + row] = vy.w;
        }
        __syncthreads();
        #pragma unroll
        for (int k = 0; k < KC; ++k) {
            float ax[8], ay[8];
            *reinterpret_cast<float4*>(&ax[0]) = *reinterpret_cast<const float4*>(&xs[k * SPAD + ty * 8]);
            *reinterpret_cast<float4*>(&ax[4]) = *reinterpret_cast<const float4*>(&xs[k * SPAD + ty * 8 + 4]);
            *reinterpret_cast<float4*>(&ay[0]) = *reinterpret_cast<const float4*>(&ys[k * SPAD + tx * 8]);
            *reinterpret_cast<float4*>(&ay[4]) = *reinterpret_cast<const float4*>(&ys[k * SPAD + tx * 8 + 4]);
            #pragma unroll
            for (int i = 0; i < 8; ++i)
                #pragma unroll
                for (int j = 0; j < 8; ++j)
                    acc[i][j] = fmaf(ax[i], ay[j], acc[i][j]);
        }
    }

    // epilogue: (1 - dot*invnx*invny)/ln2 into LDS tile [128][130]
    float rn[8], cn[8];
    #pragma unroll
    for (int i = 0; i < 8; ++i) rn[i] = invnx[b * TLEN + r0 + ty * 8 + i];
    #pragma unroll
    for (int j = 0; j < 8; ++j) cn[j] = invny[b * TLEN + c0 + tx * 8 + j];

    __syncthreads();
    float* cs = smem;
    #pragma unroll
    for (int i = 0; i < 8; ++i)
        #pragma unroll
        for (int j = 0; j < 8; ++j)
            cs[(ty * 8 + i) * 130 + tx * 8 + j] =
                (1.0f - acc[i][j] * rn[i] * cn[j]) * INV_LN2;
    __syncthreads();

    float* sk = skew + (size_t)b * (NDIAG * TLEN);
    const int wv = tid >> 6, l = tid & 63;
    for (int dd = wv; dd < 255; dd += 4) {
        int lo = max(0, dd - 127), hi = min(127, dd);
        size_t base = (size_t)(r0 + c0 + dd) * TLEN + r0;
        for (int rb = lo; rb <= hi; rb += 64) {
            int rl = rb + l;
            if (rl <= hi) sk[base + rl] = cs[rl * 129 + dd];   // rl*130 + (dd-rl)
        }
    }
}

// ----------------------------------------------------------------- DTW DP
// 8 waves per batch (512 threads), lane owns row r = tid; wave w processes
// diag kd at phase p = kd + 16w; one __syncthreads per 16-phase segment.
// Segment modes (wave-uniform): JUNK / PARTIAL(masked+clamped) / INTERIOR.
// R6 changes:
//  - cross-lane shift via DPP wave_shr:1 (VALU pipe, ~4cy) instead of
//    __shfl_up's ds-permute (~120cy on the inter-phase dependency chain).
//  - all 4 boundary quads are read ONCE at segment start: every quad
//    consumed in segment n was written at consumer-phase 16n-{13,9,5,1},
//    i.e. in segment n-1, barrier-separated from the reads. Removes the
//    mid-segment LDS read latency from the chain.

__device__ __forceinline__ int clampi(int v) {
    return v < 0 ? 0 : (v > NDIAG - 1 ? NDIAG - 1 : v);
}

__device__ __forceinline__ float dpp_shr1(float x) {
    return __builtin_bit_cast(float,
        __builtin_amdgcn_update_dpp(0, __builtin_bit_cast(int, x),
                                    0x138 /*wave_shr:1*/, 0xF, 0xF, true));
}

#define PH(s, CC, PN, PO, NQ, MASKED, CLAMPED)                                 \
  {                                                                            \
    float sh_cur = dpp_shr1(PN);                                               \
    float up_ = lane0 ? bd_up : sh_cur;                                        \
    float dg_ = lane0 ? bd_dg : sh_prev;                                       \
    float m_   = fminf(fminf(dg_, PN), up_);                                   \
    float mid_ = __builtin_amdgcn_fmed3f(dg_, PN, up_);                        \
    float mx_  = fmaxf(fmaxf(dg_, PN), up_);                                   \
    float e_   = 1.0f + __builtin_amdgcn_exp2f(m_ - mid_)                      \
                      + __builtin_amdgcn_exp2f(m_ - mx_);                      \
    float v_   = CC + m_ - __builtin_amdgcn_logf(e_);                          \
    PO = (MASKED) ? (((unsigned)(vb0 + (s)) < 512u) ? v_ : vBig) : v_;         \
    if (((s) & 3) == 0) bq.x = PO;                                             \
    if (((s) & 3) == 1) bq.y = PO;                                             \
    if (((s) & 3) == 2) bq.z = PO;                                             \
    if (((s) & 3) == 3) { bq.w = PO;                                           \
      if (lt == 63) bnd4[w + 1][(q0 + ((s) >> 2)) & 7] = bq; }                 \
    bd_dg = bd_up;                                                             \
    bd_up = ((s) & 3) == 0 ? NQ.x : ((s) & 3) == 1 ? NQ.y                      \
          : ((s) & 3) == 2 ? NQ.z : NQ.w;                                      \
    sh_prev = sh_cur;                                                          \
    { int kl_ = kd0 + (s) + 8; if (CLAMPED) kl_ = clampi(kl_);                 \
      CC = skb[(size_t)kl_ * TLEN]; }                                          \
  }

#define SEG_BODY(MASKED, CLAMPED)                                              \
    PH(0,  c0, P, Q, nq0, MASKED, CLAMPED) PH(1,  c1, Q, P, nq0, MASKED, CLAMPED) \
    PH(2,  c2, P, Q, nq0, MASKED, CLAMPED) PH(3,  c3, Q, P, nq0, MASKED, CLAMPED) \
    PH(4,  c4, P, Q, nq1, MASKED, CLAMPED) PH(5,  c5, Q, P, nq1, MASKED, CLAMPED) \
    PH(6,  c6, P, Q, nq1, MASKED, CLAMPED) PH(7,  c7, Q, P, nq1, MASKED, CLAMPED) \
    PH(8,  c0, P, Q, nq2, MASKED, CLAMPED) PH(9,  c1, Q, P, nq2, MASKED, CLAMPED) \
    PH(10, c2, P, Q, nq2, MASKED, CLAMPED) PH(11, c3, Q, P, nq2, MASKED, CLAMPED) \
    PH(12, c4, P, Q, nq3, MASKED, CLAMPED) PH(13, c5, Q, P, nq3, MASKED, CLAMPED) \
    PH(14, c6, P, Q, nq3, MASKED, CLAMPED) PH(15, c7, Q, P, nq3, MASKED, CLAMPED)

#define PRIME(K)                                                               \
    c0 = skb[(size_t)clampi((K) + 0) * TLEN];                                  \
    c1 = skb[(size_t)clampi((K) + 1) * TLEN];                                  \
    c2 = skb[(size_t)clampi((K) + 2) * TLEN];                                  \
    c3 = skb[(size_t)clampi((K) + 3) * TLEN];                                  \
    c4 = skb[(size_t)clampi((K) + 4) * TLEN];                                  \
    c5 = skb[(size_t)clampi((K) + 5) * TLEN];                                  \
    c6 = skb[(size_t)clampi((K) + 6) * TLEN];                                  \
    c7 = skb[(size_t)clampi((K) + 7) * TLEN];

__global__ __launch_bounds__(512) void sdtw_dp(const float* __restrict__ skew,
                                               float* __restrict__ out) {
    const int b   = blockIdx.x;
    const int tid = threadIdx.x;
    const int w   = tid >> 6;
    const int lt  = tid & 63;
    const bool lane0 = (lt == 0);
    const float* skb = skew + (size_t)b * (NDIAG * TLEN) + tid;   // row r = tid

    __shared__ float4 bnd4[9][8];                // [consumer wave][quad slot]
    if (tid < 288) ((float*)bnd4)[tid] = BIGV;

    float P = BIGV, Q = BIGV;
    float vBig    = BIGV;
    float sh_prev = BIGV;
    float bd_up   = BIGV;
    float bd_dg   = (w == 0) ? 0.0f : BIGV;      // R(0,0)=0 enters at kd=0, wave0
    float4 bq = make_float4(BIGV, BIGV, BIGV, BIGV);

    __syncthreads();

    float c0, c1, c2, c3, c4, c5, c6, c7;
    PRIME(-16 * w)                               // real prime for w=0; harmless else

    for (int s = 0; s < 71; ++s) {
        const int sw  = s - 5 * w;               // wave-uniform
        const int kd0 = 16 * (s - w);
        const int q0  = (kd0 >> 2) & 7;
        const int vb0 = kd0 - tid;

        if (sw >= -1 && sw <= 35) {
            // hoisted boundary quads (all written in segment s-1 -> race-free)
            float4 nq0 = bnd4[w][q0];
            float4 nq1 = bnd4[w][(q0 + 1) & 7];
            float4 nq2 = bnd4[w][(q0 + 2) & 7];
            float4 nq3 = bnd4[w][(q0 + 3) & 7];
            if (sw == -1) { PRIME(kd0) }         // warm-up: re-prime prefetch
            if (sw >= 4 && sw <= 31) { SEG_BODY(0, 0) }   // interior
            else                     { SEG_BODY(1, 1) }   // staircase/warm-up
        } else {
            if (lt == 63) {                      // junk: keep boundary cadence
                float4 bigq = make_float4(BIGV, BIGV, BIGV, BIGV);
                bnd4[w + 1][q0]           = bigq;
                bnd4[w + 1][(q0 + 1) & 7] = bigq;
                bnd4[w + 1][(q0 + 2) & 7] = bigq;
                bnd4[w + 1][(q0 + 3) & 7] = bigq;
            }
        }
        __syncthreads();
    }

    if (tid == 511) out[b] = Q * LN2;            // R'(512,512) * ln2
}

// ---------------------------------------------------------------- launcher
extern "C" void kernel_launch(void* const* d_in, const int* in_sizes, int n_in,
                              void* d_out, int out_size, void* d_ws, size_t ws_size,
                              hipStream_t stream) {
    const float* x = (const float*)d_in[0];
    const float* y = (const float*)d_in[1];
    float* outp = (float*)d_out;

    float* invnx = (float*)d_ws;                          //  16,384 floats
    float* invny = invnx + (size_t)BT * TLEN;             //  16,384 floats
    float* skew  = invny + (size_t)BT * TLEN;             //  16,760,832 floats

    sdtw_invnorm<<<dim3(BT * TLEN / 4, 2), dim3(256), 0, stream>>>(x, y, invnx, invny);
    sdtw_gemm_skew<<<dim3(4, 4, BT), dim3(256), 0, stream>>>(x, y, invnx, invny, skew);
    sdtw_dp<<<dim3(BT), dim3(512), 0, stream>>>(skew, outp);
}